// Round 2
// baseline (502.836 us; speedup 1.0000x reference)
//
#include <hip/hip_runtime.h>
#include <hip/hip_bf16.h>
#include <stdint.h>

// ---------------------------------------------------------------------------
// SelfAttention (B=2,S=2048,D=1024,H=16,DK=64), fp32 in/out, bf16 MFMA inside.
// CONSERVATIVE round: m97-verified GEMM structure (linear LDS), no XOR swizzle,
// no tr-read (scalar LDS gathers for V fragments). Goal: correctness baseline.
// Pipeline: [cast x2 -> gemm] x3 -> fused flash attention -> cast -> gemm(out)
// ---------------------------------------------------------------------------

typedef __bf16 bf16x8 __attribute__((ext_vector_type(8)));
typedef float f32x4 __attribute__((ext_vector_type(4)));

#define DEVI __device__ __forceinline__

static constexpr int S = 2048, D = 1024, H = 16, DK = 64, BATCH = 2;
static constexpr int BS = BATCH * S;  // 4096 rows for the projection GEMMs

DEVI void gload_lds16(const void* g, void* l) {
  // async global->LDS, 16B per lane; LDS dest = wave-uniform base + lane*16
  __builtin_amdgcn_global_load_lds((const __attribute__((address_space(1))) void*)g,
                                   (__attribute__((address_space(3))) void*)l, 16, 0, 0);
}

// ---------------- fp32 -> bf16 cast (8 elems/thread, exact grid) ------------
__global__ void cast_f32_to_bf16(const float* __restrict__ in, __bf16* __restrict__ out, int n) {
  int i = (blockIdx.x * blockDim.x + threadIdx.x) * 8;
  if (i >= n) return;
  float4 a = *(const float4*)(in + i);
  float4 b = *(const float4*)(in + i + 4);
  bf16x8 o;
  o[0] = (__bf16)a.x; o[1] = (__bf16)a.y; o[2] = (__bf16)a.z; o[3] = (__bf16)a.w;
  o[4] = (__bf16)b.x; o[5] = (__bf16)b.y; o[6] = (__bf16)b.z; o[7] = (__bf16)b.w;
  *(bf16x8*)(out + i) = o;
}

// ---------------- C = (A @ W^T + bias) * scale ------------------------------
// A [M,K] bf16 row-major, W [N,K] bf16 row-major (torch Linear layout).
// Exact m97 structure: 128x128 tile, BK=64, 4 waves (2x2), 16x16x32 MFMA,
// global_load_lds width-16 staging into LINEAR LDS rows, ds_read_b128 frags.
template <bool OUT_BF16>
__global__ void gemm_bt(const __bf16* __restrict__ A, const __bf16* __restrict__ W,
                        const float* __restrict__ bias, void* __restrict__ out,
                        float scale, int M, int N, int K) {
  __shared__ __bf16 As[128 * 64];
  __shared__ __bf16 Bs[128 * 64];
  const int t = threadIdx.x;
  const int w = t >> 6, l = t & 63;
  const int c = l & 15, g = l >> 4;
  const int wr = w >> 1, wc = w & 1;
  const int m0 = blockIdx.x * 128, n0 = blockIdx.y * 128;

  // staging: issue i covers rows i*32 + w*8 + (l>>3); in-row chunk = (l&7)*8 elems
  const int srow = (w << 3) + (l >> 3);
  const int scol = (l & 7) << 3;  // LINEAR (no swizzle)
  char* AsB = (char*)As;
  char* BsB = (char*)Bs;

  f32x4 acc[4][4] = {};

  for (int k0 = 0; k0 < K; k0 += 64) {
#pragma unroll
    for (int i = 0; i < 4; ++i) {
      int row = (i << 5) + srow;
      gload_lds16(A + (size_t)(m0 + row) * K + k0 + scol, AsB + (i << 12) + (w << 10));
      gload_lds16(W + (size_t)(n0 + row) * K + k0 + scol, BsB + (i << 12) + (w << 10));
    }
    __syncthreads();  // compiler emits vmcnt(0) drain before s_barrier
#pragma unroll
    for (int kf = 0; kf < 2; ++kf) {
      bf16x8 a[4], b[4];
#pragma unroll
      for (int mi = 0; mi < 4; ++mi) {
        int rowA = (wr << 6) + (mi << 4) + c;
        int rowB = (wc << 6) + (mi << 4) + c;
        a[mi] = *(const bf16x8*)(AsB + rowA * 128 + (kf << 6) + (g << 4));
        b[mi] = *(const bf16x8*)(BsB + rowB * 128 + (kf << 6) + (g << 4));
      }
#pragma unroll
      for (int mi = 0; mi < 4; ++mi)
#pragma unroll
        for (int ni = 0; ni < 4; ++ni)
          acc[mi][ni] = __builtin_amdgcn_mfma_f32_16x16x32_bf16(a[mi], b[ni], acc[mi][ni], 0, 0, 0);
    }
    __syncthreads();
  }

  // epilogue: C/D layout col = lane&15, row = (lane>>4)*4 + r  (m89-verified)
#pragma unroll
  for (int ni = 0; ni < 4; ++ni) {
    int col = n0 + (wc << 6) + (ni << 4) + c;
    float bv = bias[col];
#pragma unroll
    for (int mi = 0; mi < 4; ++mi) {
#pragma unroll
      for (int r = 0; r < 4; ++r) {
        int row = m0 + (wr << 6) + (mi << 4) + (g << 2) + r;
        float v = (acc[mi][ni][r] + bv) * scale;
        if (OUT_BF16) ((__bf16*)out)[(size_t)row * N + col] = (__bf16)v;
        else          ((float*)out)[(size_t)row * N + col] = v;
      }
    }
  }
}

// ---------------- fused flash attention -------------------------------------
// grid (S/16, H/4, B), 256 threads. Wave w handles head h = blockIdx.y*4 + w,
// q-rows [q0, q0+16). All 4 waves read the SAME mask tile -> L1/L2 dedup.
// Per k-iter (KBLK=32): stage K,V linear row-major [32][64] via global_load_lds,
// QK^T MFMA, online softmax (denominator without mask1), P*mask1 -> LDS,
// PV MFMA with scalar ds_read V-fragments (correct-by-construction).
__global__ void attn_fused(const __bf16* __restrict__ Qb, const __bf16* __restrict__ Kb,
                           const __bf16* __restrict__ Vb, const float* __restrict__ mask,
                           const float* __restrict__ mask1, __bf16* __restrict__ outb) {
  __shared__ __bf16 Ks[4][32 * 64];   // per-wave, linear row-major
  __shared__ __bf16 Vs[4][32 * 64];   // per-wave, linear row-major
  __shared__ __bf16 Ps[4][16 * 40];   // per-wave P tile, rows padded to 40 elems

  const int t = threadIdx.x, w = t >> 6, l = t & 63;
  const int c = l & 15, g = l >> 4;
  const int q0 = blockIdx.x << 4;
  const int h = (blockIdx.y << 2) + w;
  const int b = blockIdx.z;
  const size_t bh = (size_t)b * H + h;
  const __bf16* Qh = Qb + bh * S * DK;
  const __bf16* Kh = Kb + bh * S * DK;
  const __bf16* Vh = Vb + bh * S * DK;
  const float* mk_base = mask + (size_t)b * S * S;
  const float* m1_base = mask1 + (size_t)b * S * S;

  // Q fragments hoisted (NORM already folded into the Q projection epilogue).
  // A-layout: lane holds A[row=l&15][k=(l>>4)*8 + j]
  bf16x8 qf0 = *(const bf16x8*)(Qh + (q0 + c) * DK + (g << 3));
  bf16x8 qf1 = *(const bf16x8*)(Qh + (q0 + c) * DK + 32 + (g << 3));

  // staging: issue i covers rows i*8 + (l>>3), chunk (l&7)*8 elems (linear)
  const int krow = l >> 3;
  const int kcol = (l & 7) << 3;

  char* KsB = (char*)&Ks[w][0];
  char* VsB = (char*)&Vs[w][0];
  const __bf16* Vsp = &Vs[w][0];

  float mrun[4] = {-1e30f, -1e30f, -1e30f, -1e30f};
  float lrun[4] = {0.f, 0.f, 0.f, 0.f};
  f32x4 acc[4] = {};

  for (int k0 = 0; k0 < S; k0 += 32) {
#pragma unroll
    for (int i = 0; i < 4; ++i) {
      gload_lds16(Kh + (size_t)(k0 + (i << 3) + krow) * DK + kcol, KsB + (i << 10));
      gload_lds16(Vh + (size_t)(k0 + (i << 3) + krow) * DK + kcol, VsB + (i << 10));
    }
    // mask tiles, addressed in C/D layout (row = g*4+r, col = kt*16+c)
    float mk[2][4], m1[2][4];
#pragma unroll
    for (int kt = 0; kt < 2; ++kt)
#pragma unroll
      for (int r = 0; r < 4; ++r) {
        size_t idx = (size_t)(q0 + (g << 2) + r) * S + (size_t)(k0 + (kt << 4) + c);
        mk[kt][r] = mk_base[idx];
        m1[kt][r] = m1_base[idx];
      }
    __syncthreads();  // drains vmcnt(0): staged K/V visible

    // QK^T: D[q=(g*4+r)][kp=c] per kt half; B-frag lane holds K[kp=c][d=(l>>4)*8+j]
    f32x4 sc[2];
#pragma unroll
    for (int kt = 0; kt < 2; ++kt) {
      int row = (kt << 4) + c;
      bf16x8 kf0 = *(const bf16x8*)(KsB + row * 128 + (g << 4));
      bf16x8 kf1 = *(const bf16x8*)(KsB + row * 128 + 64 + (g << 4));
      f32x4 z = {};
      z = __builtin_amdgcn_mfma_f32_16x16x32_bf16(qf0, kf0, z, 0, 0, 0);
      z = __builtin_amdgcn_mfma_f32_16x16x32_bf16(qf1, kf1, z, 0, 0, 0);
      sc[kt] = z;
    }

    // online softmax per q-row (16 kp live across the 16 lanes of group g)
    float alpha[4];
#pragma unroll
    for (int r = 0; r < 4; ++r) {
      float l0 = sc[0][r] + mk[0][r];
      float l1 = sc[1][r] + mk[1][r];
      float mx = fmaxf(l0, l1);
      mx = fmaxf(mx, __shfl_xor(mx, 1));
      mx = fmaxf(mx, __shfl_xor(mx, 2));
      mx = fmaxf(mx, __shfl_xor(mx, 4));
      mx = fmaxf(mx, __shfl_xor(mx, 8));
      float mnew = fmaxf(mrun[r], mx);
      float al = __expf(mrun[r] - mnew);
      mrun[r] = mnew;
      alpha[r] = al;
      float p0 = __expf(l0 - mnew);
      float p1 = __expf(l1 - mnew);
      float rs = p0 + p1;
      rs += __shfl_xor(rs, 1);
      rs += __shfl_xor(rs, 2);
      rs += __shfl_xor(rs, 4);
      rs += __shfl_xor(rs, 8);
      lrun[r] = lrun[r] * al + rs;  // denominator WITHOUT mask1 (post-softmax mul)
      Ps[w][((g << 2) + r) * 40 + c] = (__bf16)(p0 * m1[0][r]);
      Ps[w][((g << 2) + r) * 40 + 16 + c] = (__bf16)(p1 * m1[1][r]);
    }
#pragma unroll
    for (int ni = 0; ni < 4; ++ni) {
      acc[ni][0] *= alpha[0];
      acc[ni][1] *= alpha[1];
      acc[ni][2] *= alpha[2];
      acc[ni][3] *= alpha[3];
    }

    // PV: A-frag = P[q=c][kp=g*8+j] (row-major read);
    // B-frag = V[kp=g*8+j][dv=ni*16+c] via scalar LDS gathers (stride 64 elems)
    bf16x8 pf = *(const bf16x8*)&Ps[w][c * 40 + (g << 3)];
    const __bf16* Vrow = Vsp + (g << 9) + c;  // (g*8)*64 + c
#pragma unroll
    for (int ni = 0; ni < 4; ++ni) {
      bf16x8 vf;
#pragma unroll
      for (int j = 0; j < 8; ++j) vf[j] = Vrow[(j << 6) + (ni << 4)];
      acc[ni] = __builtin_amdgcn_mfma_f32_16x16x32_bf16(pf, vf, acc[ni], 0, 0, 0);
    }
  }

  float inv[4];
#pragma unroll
  for (int r = 0; r < 4; ++r) inv[r] = 1.0f / lrun[r];
  __bf16* oh = outb + bh * S * DK;
#pragma unroll
  for (int ni = 0; ni < 4; ++ni)
#pragma unroll
    for (int r = 0; r < 4; ++r)
      oh[(size_t)(q0 + (g << 2) + r) * DK + (ni << 4) + c] = (__bf16)(acc[ni][r] * inv[r]);
}

// ---------------------------------------------------------------------------
extern "C" void kernel_launch(void* const* d_in, const int* in_sizes, int n_in,
                              void* d_out, int out_size, void* d_ws, size_t ws_size,
                              hipStream_t stream) {
  (void)in_sizes; (void)n_in; (void)out_size; (void)ws_size;
  const float* q   = (const float*)d_in[0];
  const float* k   = (const float*)d_in[1];
  const float* v   = (const float*)d_in[2];
  const float* am  = (const float*)d_in[3];
  const float* am1 = (const float*)d_in[4];
  const float* wq  = (const float*)d_in[5];
  const float* bq  = (const float*)d_in[6];
  const float* wk  = (const float*)d_in[7];
  const float* bk  = (const float*)d_in[8];
  const float* wv  = (const float*)d_in[9];
  const float* bv  = (const float*)d_in[10];
  const float* wo  = (const float*)d_in[11];
  const float* bo  = (const float*)d_in[12];

  const size_t NX = (size_t)BS * D;  // 4,194,304 elems
  const size_t NW = (size_t)D * D;   // 1,048,576 elems
  // ws layout (sequential buffer reuse, total ~34 MB):
  char* ws = (char*)d_ws;
  __bf16* xbf = (__bf16*)ws;      // activation input, reused q->k->v  (8 MB)
  __bf16* wb  = xbf + NX;         // weight, reused wq->wk->wv->wo     (2 MB)
  __bf16* Qp  = wb + NW;          // projected Q (bf16, *NORM)         (8 MB)
  __bf16* Kp  = Qp + NX;          //                                    (8 MB)
  __bf16* Vp  = Kp + NX;          //                                    (8 MB)
  __bf16* Vl  = xbf;              // attention out reuses xbf (dead by then)

  auto cast = [&](const float* src, __bf16* dst, size_t n) {
    cast_f32_to_bf16<<<(int)(n / 8 / 256), 256, 0, stream>>>(src, dst, (int)n);
  };

  dim3 gg(BS / 128, D / 128);  // 32 x 8 = 256 blocks
  const float NORM = 0.125f;   // 1/sqrt(DK); folded into Q projection

  cast(q, xbf, NX);
  cast(wq, wb, NW);
  gemm_bt<true><<<gg, 256, 0, stream>>>(xbf, wb, bq, Qp, NORM, BS, D, D);
  cast(k, xbf, NX);
  cast(wk, wb, NW);
  gemm_bt<true><<<gg, 256, 0, stream>>>(xbf, wb, bk, Kp, 1.0f, BS, D, D);
  cast(v, xbf, NX);
  cast(wv, wb, NW);
  gemm_bt<true><<<gg, 256, 0, stream>>>(xbf, wb, bv, Vp, 1.0f, BS, D, D);

  dim3 ga(S / 16, H / 4, BATCH);  // 128 x 4 x 2 = 1024 blocks
  attn_fused<<<ga, 256, 0, stream>>>(Qp, Kp, Vp, am, am1, Vl);

  cast(wo, wb, NW);
  gemm_bt<false><<<gg, 256, 0, stream>>>(Vl, wb, bo, d_out, 1.0f, BS, D, D);
}